// Round 6
// baseline (671.786 us; speedup 1.0000x reference)
//
#include <hip/hip_runtime.h>

// TemporalTX: T=512, B=16, D=128, H=8, DH=128, P=512, J=1024.
// INPUTS fp32; OUTPUT fp32. Workspace intermediates bf16.
// out = [layer_out (1M) | inputs copy (1M) | layer_out copy (1M)] fp32 elems.

typedef short s16x8 __attribute__((ext_vector_type(8)));
typedef float f32x4 __attribute__((ext_vector_type(4)));

#define MFMA(a, b, c) __builtin_amdgcn_mfma_f32_16x16x32_bf16((a), (b), (c), 0, 0, 0)
#define LDS_FENCE() asm volatile("s_waitcnt lgkmcnt(0)" ::: "memory")

__device__ __forceinline__ unsigned short f2b(float f) {
  unsigned int x = __builtin_bit_cast(unsigned int, f);
  x += 0x7fffu + ((x >> 16) & 1u);   // RNE
  return (unsigned short)(x >> 16);
}
__device__ __forceinline__ s16x8 ldg8(const unsigned short* p) {  // bf16 x8 (ws)
  return *(const s16x8*)p;
}
__device__ __forceinline__ s16x8 ldf8(const float* p) {  // fp32 x8 -> bf16 x8
  float4 u = ((const float4*)p)[0];
  float4 v = ((const float4*)p)[1];
  s16x8 r;
  r[0] = (short)f2b(u.x); r[1] = (short)f2b(u.y);
  r[2] = (short)f2b(u.z); r[3] = (short)f2b(u.w);
  r[4] = (short)f2b(v.x); r[5] = (short)f2b(v.y);
  r[6] = (short)f2b(v.z); r[7] = (short)f2b(v.w);
  return r;
}

// ---------------------------------------------------------------------------
// KV projection over xm = cat(mem0, x):  kv[j][b][f] = sum_e xm[j][b][e]*wkv[f][e]
// Block shares (nc, b); waves split j (4x weight-chunk reuse via L1/L2).
__global__ __launch_bounds__(256, 4) void k_gemm_kv(
    const float* __restrict__ x, const float* __restrict__ mem,
    const float* __restrict__ wkv,
    unsigned short* __restrict__ Kk, unsigned short* __restrict__ Vt) {
  __shared__ float tbuf[4][16][128];
  const int lane = threadIdx.x & 63;
  const int w = threadIdx.x >> 6;
  const int nc = blockIdx.x & 15;          // weight chunk (block-uniform)
  const int b = (blockIdx.x >> 4) & 15;    // batch (block-uniform)
  const int j0 = (blockIdx.x >> 8) * 64 + w * 16;  // 0..1008
  const int l15 = lane & 15, l4 = lane >> 4;

  const int jr = j0 + l15;
  const float* arow =
      (jr < 512 ? mem + (jr * 16 + b) * 128 : x + ((jr - 512) * 16 + b) * 128) + l4 * 8;
  s16x8 a0 = ldf8(arow), a1 = ldf8(arow + 32), a2 = ldf8(arow + 64), a3 = ldf8(arow + 96);

  f32x4 acc[8] = {};
#pragma unroll
  for (int fc = 0; fc < 8; ++fc) {
    const float* brow = wkv + (nc * 128 + fc * 16 + l15) * 128 + l4 * 8;
    acc[fc] = MFMA(a0, ldf8(brow), acc[fc]);
    acc[fc] = MFMA(a1, ldf8(brow + 32), acc[fc]);
    acc[fc] = MFMA(a2, ldf8(brow + 64), acc[fc]);
    acc[fc] = MFMA(a3, ldf8(brow + 96), acc[fc]);
  }

  if (nc < 8) {  // K part, h = nc
#pragma unroll
    for (int fc = 0; fc < 8; ++fc)
#pragma unroll
      for (int r = 0; r < 4; ++r) {
        int j = j0 + l4 * 4 + r;
        Kk[((b * 8 + nc) * 1024 + j) * 128 + fc * 16 + l15] = f2b(acc[fc][r]);
      }
  } else {  // V part, h = nc-8: transpose 16j x 128d -> Vt rows d (j contig)
    const int h = nc - 8;
#pragma unroll
    for (int fc = 0; fc < 8; ++fc)
#pragma unroll
      for (int r = 0; r < 4; ++r) tbuf[w][l4 * 4 + r][fc * 16 + l15] = acc[fc][r];
    LDS_FENCE();  // per-wave slice; same-wave ds ordering (verified r3==r4)
#pragma unroll
    for (int half = 0; half < 2; ++half) {
      int dd = half * 64 + lane;
      unsigned int wd[8];
#pragma unroll
      for (int pw = 0; pw < 8; ++pw) {
        unsigned int lo = f2b(tbuf[w][2 * pw][dd]);
        unsigned int hi = f2b(tbuf[w][2 * pw + 1][dd]);
        wd[pw] = lo | (hi << 16);
      }
      unsigned short* dst = Vt + ((b * 8 + h) * 128 + dd) * 1024 + j0;
      ((uint4*)dst)[0] = make_uint4(wd[0], wd[1], wd[2], wd[3]);
      ((uint4*)dst)[1] = make_uint4(wd[4], wd[5], wd[6], wd[7]);
    }
  }
}

// ---------------------------------------------------------------------------
// P projection: P[h][c][d] = sum_e pe[c][e] * wp[h*128+d][e], pe analytic.
// Block shares nc; waves split c.
__global__ __launch_bounds__(256, 4) void k_gemm_p(
    const float* __restrict__ wp, unsigned short* __restrict__ Pp) {
  const int lane = threadIdx.x & 63;
  const int w = threadIdx.x >> 6;
  const int nc = blockIdx.x & 7;
  const int c0 = ((blockIdx.x >> 3) * 4 + w) * 16;
  const int l15 = lane & 15, l4 = lane >> 4;

  const float pos = (float)(1023 - (c0 + l15));
  s16x8 a[4];
#pragma unroll
  for (int ks = 0; ks < 4; ++ks)
#pragma unroll
    for (int jj = 0; jj < 8; ++jj) {
      int e = ks * 32 + l4 * 8 + jj;
      int t = e & 63;
      float ang = pos * exp2f(-0.20762050593046014f * (float)t);  // 10000^(-t/64)
      float val = (e < 64) ? sinf(ang) : cosf(ang);
      a[ks][jj] = (short)f2b(val);
    }

  f32x4 acc[8] = {};
#pragma unroll
  for (int fc = 0; fc < 8; ++fc) {
    const float* brow = wp + (nc * 128 + fc * 16 + l15) * 128 + l4 * 8;
    acc[fc] = MFMA(a[0], ldf8(brow), acc[fc]);
    acc[fc] = MFMA(a[1], ldf8(brow + 32), acc[fc]);
    acc[fc] = MFMA(a[2], ldf8(brow + 64), acc[fc]);
    acc[fc] = MFMA(a[3], ldf8(brow + 96), acc[fc]);
  }
#pragma unroll
  for (int fc = 0; fc < 8; ++fc)
#pragma unroll
    for (int r = 0; r < 4; ++r)
      Pp[(nc * 1024 + c0 + l4 * 4 + r) * 128 + fc * 16 + l15] = f2b(acc[fc][r]);
}

// ---------------------------------------------------------------------------
// Flash attention with TXL relative position, Q-projection fused in prologue.
// One wave = 16 q-rows of one (b,h). Barrier-free: per-wave LDS slice + fences
// (bit-identical shfl band gather verified r3==r4). LDS 33.8 KB -> 4 blocks/CU.
__global__ __launch_bounds__(256, 4) void k_flash(
    const float* __restrict__ x, const float* __restrict__ wq,
    const unsigned short* __restrict__ Kk, const unsigned short* __restrict__ Vt,
    const unsigned short* __restrict__ Pp,
    const float* __restrict__ uu, const float* __restrict__ vv,
    unsigned short* __restrict__ OA) {
  // aliased: prologue q-transform (qu cols 0..127, qv cols 136..263);
  // loop probs (cols 0..63). stride 264 shorts => 2-way bank alias (free).
  __shared__ __align__(16) unsigned short smem[4][16][264];
  const int lane = threadIdx.x & 63;
  const int w = threadIdx.x >> 6;
  const int bh = blockIdx.x & 127;   // same bh -> same XCD round-robin slot
  const int grp = blockIdx.x >> 7;   // 0..7
  const int iw = grp * 64 + w * 16;  // 16-row q tile base
  const int b = bh >> 3, h = bh & 7;
  const int l15 = lane & 15, l4 = lane >> 4;
  const float CSCALE = 0.08838834764831845f * 1.4426950408889634f;  // 1/sqrt(128)*log2e

  const unsigned short* K_b = Kk + bh * (1024 * 128);
  const unsigned short* V_b = Vt + bh * (128 * 1024);
  const unsigned short* P_h = Pp + h * (1024 * 128);

  // ---- fused Q projection: q[iw+m][d] = sum_e x[iw+m][b][e] * wq[h*128+d][e]
  s16x8 qu[4], qv[4];
  {
    const float* arow = x + ((iw + l15) * 16 + b) * 128 + l4 * 8;
    s16x8 a0 = ldf8(arow), a1 = ldf8(arow + 32), a2 = ldf8(arow + 64), a3 = ldf8(arow + 96);
    f32x4 qd[8] = {};
#pragma unroll
    for (int fc = 0; fc < 8; ++fc) {
      const float* brow = wq + (h * 128 + fc * 16 + l15) * 128 + l4 * 8;
      qd[fc] = MFMA(a0, ldf8(brow), qd[fc]);
      qd[fc] = MFMA(a1, ldf8(brow + 32), qd[fc]);
      qd[fc] = MFMA(a2, ldf8(brow + 64), qd[fc]);
      qd[fc] = MFMA(a3, ldf8(brow + 96), qd[fc]);
    }
    // D-layout -> LDS (row m=l4*4+r), u/v biases folded
#pragma unroll
    for (int fc = 0; fc < 8; ++fc) {
      float ud = uu[h * 128 + fc * 16 + l15];
      float vd = vv[h * 128 + fc * 16 + l15];
#pragma unroll
      for (int r = 0; r < 4; ++r) {
        smem[w][l4 * 4 + r][fc * 16 + l15] = f2b(qd[fc][r] + ud);
        smem[w][l4 * 4 + r][136 + fc * 16 + l15] = f2b(qd[fc][r] + vd);
      }
    }
    LDS_FENCE();
#pragma unroll
    for (int ks = 0; ks < 4; ++ks) {
      qu[ks] = *(const s16x8*)&smem[w][l15][ks * 32 + l4 * 8];
      qv[ks] = *(const s16x8*)&smem[w][l15][136 + ks * 32 + l4 * 8];
    }
  }

  f32x4 O[8] = {};
  float mrow[4], lrow[4];
#pragma unroll
  for (int r = 0; r < 4; ++r) { mrow[r] = -1e4f; lrow[r] = 0.f; }

  const int ntiles = (iw + 591) >> 6;  // covers j <= iw+15+512, per-wave
  for (int t = 0; t < ntiles; ++t) {
    const int j0 = t * 64;
    const int c0 = j0 - iw + 496;  // band: c = j-i+511; local cc = jj-li+15 in [0,78]

    f32x4 sc[4] = {};
#pragma unroll
    for (int fc = 0; fc < 4; ++fc) {
      const unsigned short* kr = K_b + (j0 + fc * 16 + l15) * 128 + l4 * 8;
#pragma unroll
      for (int ks = 0; ks < 4; ++ks) sc[fc] = MFMA(qu[ks], ldg8(kr + ks * 32), sc[fc]);
    }
    f32x4 sp[5] = {};
#pragma unroll
    for (int pc = 0; pc < 5; ++pc) {
      int c = c0 + pc * 16 + l15;
      c = (c > 1023) ? 1023 : c;  // clamped rows feed only masked elements
      const unsigned short* pr = P_h + c * 128 + l4 * 8;
#pragma unroll
      for (int ks = 0; ks < 4; ++ks) sp[pc] = MFMA(qv[ks], ldg8(pr + ks * 32), sp[pc]);
    }

    // combine content + shfl-gathered position diagonal, mask, scale
    float mt[4] = {-1e4f, -1e4f, -1e4f, -1e4f};
#pragma unroll
    for (int fc = 0; fc < 4; ++fc)
#pragma unroll
      for (int r = 0; r < 4; ++r) {
        int li = l4 * 4 + r;
        int jj = fc * 16 + l15;
        int cc = jj - li + 15;  // cc>>4 in {fc, fc+1}
        int src = (lane & 48) | (cc & 15);
        float g0 = __shfl(sp[fc][r], src, 64);
        float g1 = __shfl(sp[fc + 1][r], src, 64);
        float pv = ((cc >> 4) == fc) ? g0 : g1;
        float logit = (sc[fc][r] + pv) * CSCALE;
        if (j0 + jj > iw + li + 512) logit = -60.0f;  // masked (exp2 ~ 1e-18)
        sc[fc][r] = logit;
        mt[r] = fmaxf(mt[r], logit);
      }

    float alpha[4];
#pragma unroll
    for (int r = 0; r < 4; ++r) {
      float m = mt[r];
#pragma unroll
      for (int off = 1; off < 16; off <<= 1) m = fmaxf(m, __shfl_xor(m, off, 64));
      float mn = fmaxf(mrow[r], m);
      alpha[r] = exp2f(mrow[r] - mn);
      mrow[r] = mn;
    }

    LDS_FENCE();  // prior pa reads drained before overwriting probs
    float rs[4] = {0.f, 0.f, 0.f, 0.f};
#pragma unroll
    for (int fc = 0; fc < 4; ++fc)
#pragma unroll
      for (int r = 0; r < 4; ++r) {
        float p = exp2f(sc[fc][r] - mrow[r]);
        rs[r] += p;
        smem[w][l4 * 4 + r][fc * 16 + l15] = f2b(p);
      }
#pragma unroll
    for (int r = 0; r < 4; ++r) {
      float s = rs[r];
#pragma unroll
      for (int off = 1; off < 16; off <<= 1) s += __shfl_xor(s, off, 64);
      lrow[r] = lrow[r] * alpha[r] + s;
    }
#pragma unroll
    for (int fd = 0; fd < 8; ++fd)
#pragma unroll
      for (int r = 0; r < 4; ++r) O[fd][r] *= alpha[r];

    LDS_FENCE();  // probs written -> A-layout read
    const unsigned short* pb = &smem[w][l15][0];
    s16x8 pa0 = *(const s16x8*)(pb + l4 * 8);
    s16x8 pa1 = *(const s16x8*)(pb + 32 + l4 * 8);
#pragma unroll
    for (int fd = 0; fd < 8; ++fd) {
      const unsigned short* vr = V_b + (fd * 16 + l15) * 1024 + j0 + l4 * 8;
      O[fd] = MFMA(pa0, ldg8(vr), O[fd]);
      O[fd] = MFMA(pa1, ldg8(vr + 32), O[fd]);
    }
  }

  // epilogue: O/l -> OA[i][b][h*128+d]
#pragma unroll
  for (int fd = 0; fd < 8; ++fd)
#pragma unroll
    for (int r = 0; r < 4; ++r) {
      int li = l4 * 4 + r;
      float o = O[fd][r] / fmaxf(lrow[r], 1e-30f);
      OA[((iw + li) * 16 + b) * 1024 + h * 128 + fd * 16 + l15] = f2b(o);
    }
}

// ---------------------------------------------------------------------------
// Output projection: out[i][b][e] = sum_f OA[i][b][f] * wout[e][f], K=1024.
// Block shares wout half; waves split rows. fp32 OUTPUT: layer_out -> out[0]
// and out[2M]; raw fp32 inputs -> out[1M].
__global__ __launch_bounds__(256, 4) void k_out(
    const unsigned short* __restrict__ OA, const float* __restrict__ wout,
    const float* __restrict__ x, float* __restrict__ out) {
  const int lane = threadIdx.x & 63;
  const int w = threadIdx.x >> 6;
  const int half = blockIdx.x & 1;            // block-uniform weight chunk
  const int rt = (blockIdx.x >> 1) * 4 + w;   // i-tile 0..511
  const int l15 = lane & 15, l4 = lane >> 4;

  f32x4 acc[4] = {};
  const unsigned short* arow = OA + (rt * 16 + l15) * 1024 + l4 * 8;
#pragma unroll 4
  for (int ks = 0; ks < 32; ++ks) {
    s16x8 a = ldg8(arow + ks * 32);
#pragma unroll
    for (int fc = 0; fc < 4; ++fc) {
      const float* brow = wout + (half * 64 + fc * 16 + l15) * 1024 + ks * 32 + l4 * 8;
      acc[fc] = MFMA(a, ldf8(brow), acc[fc]);
    }
  }
#pragma unroll
  for (int fc = 0; fc < 4; ++fc)
#pragma unroll
    for (int r = 0; r < 4; ++r) {
      int rg = rt * 16 + l4 * 4 + r;
      int e = half * 64 + fc * 16 + l15;
      float v = acc[fc][r];
      out[rg * 128 + e] = v;
      out[2097152 + rg * 128 + e] = v;
    }
  // copy inputs (fp32) -> out1 (fp32, exact), 1024 floats per wave-chunk
  const float4* src = (const float4*)(x + rt * 2048 + half * 1024);
  float4* dst = (float4*)(out + 1048576 + rt * 2048 + half * 1024);
  dst[lane] = src[lane];
  dst[64 + lane] = src[64 + lane];
  dst[128 + lane] = src[128 + lane];
  dst[192 + lane] = src[192 + lane];
}

// ---------------------------------------------------------------------------
extern "C" void kernel_launch(void* const* d_in, const int* in_sizes, int n_in,
                              void* d_out, int out_size, void* d_ws, size_t ws_size,
                              hipStream_t stream) {
  (void)in_sizes; (void)n_in; (void)out_size; (void)ws_size;
  const float* x    = (const float*)d_in[0];  // [512][16][128] fp32
  const float* mem  = (const float*)d_in[1];  // [2][512][16][128] fp32
  const float* wkv  = (const float*)d_in[2];  // [2048][128] fp32
  const float* wq   = (const float*)d_in[3];  // [1024][128] fp32
  const float* wp   = (const float*)d_in[4];  // [1024][128] fp32
  const float* wout = (const float*)d_in[5];  // [128][1024] fp32
  const float* uu   = (const float*)d_in[6];  // [8][128] fp32
  const float* vv   = (const float*)d_in[7];  // [8][128] fp32
  float* out = (float*)d_out;                 // fp32, 3,145,728 elems
  unsigned short* ws = (unsigned short*)d_ws;

  unsigned short* Kk = ws;             // [16][8][1024][128] 16,777,216
  unsigned short* Vt = ws + 16777216;  // [16][8][128][1024] 16,777,216
  unsigned short* Pp = ws + 33554432;  // [8][1024][128]      1,048,576
  unsigned short* OA = ws + 34603008;  // [512][16][1024]     8,388,608
  // total ws: 42,991,616 bf16 elems = ~82 MB

  k_gemm_kv<<<4096, 256, 0, stream>>>(x, mem, wkv, Kk, Vt);
  k_gemm_p<<<128, 256, 0, stream>>>(wp, Pp);
  k_flash<<<1024, 256, 0, stream>>>(x, wq, Kk, Vt, Pp, uu, vv, OA);
  k_out<<<256, 256, 0, stream>>>(OA, wout, x, out);
}

// Round 7
// 639.021 us; speedup vs baseline: 1.0513x; 1.0513x over previous
//
#include <hip/hip_runtime.h>

// TemporalTX: T=512, B=16, D=128, H=8, DH=128, P=512, J=1024.
// INPUTS fp32; OUTPUT fp32. Workspace intermediates bf16.
// out = [layer_out (1M) | inputs copy (1M) | layer_out copy (1M)] fp32 elems.

typedef short s16x8 __attribute__((ext_vector_type(8)));
typedef float f32x4 __attribute__((ext_vector_type(4)));

#define MFMA(a, b, c) __builtin_amdgcn_mfma_f32_16x16x32_bf16((a), (b), (c), 0, 0, 0)
#define LDS_FENCE() asm volatile("s_waitcnt lgkmcnt(0)" ::: "memory")

__device__ __forceinline__ unsigned short f2b(float f) {
  unsigned int x = __builtin_bit_cast(unsigned int, f);
  x += 0x7fffu + ((x >> 16) & 1u);   // RNE
  return (unsigned short)(x >> 16);
}
__device__ __forceinline__ s16x8 ldg8(const unsigned short* p) {  // bf16 x8 (ws)
  return *(const s16x8*)p;
}
__device__ __forceinline__ s16x8 ldf8(const float* p) {  // fp32 x8 -> bf16 x8
  float4 u = ((const float4*)p)[0];
  float4 v = ((const float4*)p)[1];
  s16x8 r;
  r[0] = (short)f2b(u.x); r[1] = (short)f2b(u.y);
  r[2] = (short)f2b(u.z); r[3] = (short)f2b(u.w);
  r[4] = (short)f2b(v.x); r[5] = (short)f2b(v.y);
  r[6] = (short)f2b(v.z); r[7] = (short)f2b(v.w);
  return r;
}

// ---------------------------------------------------------------------------
// KV projection over xm = cat(mem0, x):  kv[j][b][f] = sum_e xm[j][b][e]*wkv[f][e]
// Block shares (nc, b); waves split j (4x weight-chunk reuse via L1/L2).
__global__ __launch_bounds__(256, 2) void k_gemm_kv(
    const float* __restrict__ x, const float* __restrict__ mem,
    const float* __restrict__ wkv,
    unsigned short* __restrict__ Kk, unsigned short* __restrict__ Vt) {
  __shared__ float tbuf[4][16][128];
  const int lane = threadIdx.x & 63;
  const int w = threadIdx.x >> 6;
  const int nc = blockIdx.x & 15;          // weight chunk (block-uniform)
  const int b = (blockIdx.x >> 4) & 15;    // batch (block-uniform)
  const int j0 = (blockIdx.x >> 8) * 64 + w * 16;  // 0..1008
  const int l15 = lane & 15, l4 = lane >> 4;

  const int jr = j0 + l15;
  const float* arow =
      (jr < 512 ? mem + (jr * 16 + b) * 128 : x + ((jr - 512) * 16 + b) * 128) + l4 * 8;
  s16x8 a0 = ldf8(arow), a1 = ldf8(arow + 32), a2 = ldf8(arow + 64), a3 = ldf8(arow + 96);

  f32x4 acc[8] = {};
#pragma unroll
  for (int fc = 0; fc < 8; ++fc) {
    const float* brow = wkv + (nc * 128 + fc * 16 + l15) * 128 + l4 * 8;
    acc[fc] = MFMA(a0, ldf8(brow), acc[fc]);
    acc[fc] = MFMA(a1, ldf8(brow + 32), acc[fc]);
    acc[fc] = MFMA(a2, ldf8(brow + 64), acc[fc]);
    acc[fc] = MFMA(a3, ldf8(brow + 96), acc[fc]);
  }

  if (nc < 8) {  // K part, h = nc
#pragma unroll
    for (int fc = 0; fc < 8; ++fc)
#pragma unroll
      for (int r = 0; r < 4; ++r) {
        int j = j0 + l4 * 4 + r;
        Kk[((b * 8 + nc) * 1024 + j) * 128 + fc * 16 + l15] = f2b(acc[fc][r]);
      }
  } else {  // V part, h = nc-8: transpose 16j x 128d -> Vt rows d (j contig)
    const int h = nc - 8;
#pragma unroll
    for (int fc = 0; fc < 8; ++fc)
#pragma unroll
      for (int r = 0; r < 4; ++r) tbuf[w][l4 * 4 + r][fc * 16 + l15] = acc[fc][r];
    LDS_FENCE();  // per-wave slice; same-wave ds ordering (verified r3==r4)
#pragma unroll
    for (int half = 0; half < 2; ++half) {
      int dd = half * 64 + lane;
      unsigned int wd[8];
#pragma unroll
      for (int pw = 0; pw < 8; ++pw) {
        unsigned int lo = f2b(tbuf[w][2 * pw][dd]);
        unsigned int hi = f2b(tbuf[w][2 * pw + 1][dd]);
        wd[pw] = lo | (hi << 16);
      }
      unsigned short* dst = Vt + ((b * 8 + h) * 128 + dd) * 1024 + j0;
      ((uint4*)dst)[0] = make_uint4(wd[0], wd[1], wd[2], wd[3]);
      ((uint4*)dst)[1] = make_uint4(wd[4], wd[5], wd[6], wd[7]);
    }
  }
}

// ---------------------------------------------------------------------------
// P projection: P[h][c][d] = sum_e pe[c][e] * wp[h*128+d][e], pe analytic.
// Block shares nc; waves split c.
__global__ __launch_bounds__(256, 2) void k_gemm_p(
    const float* __restrict__ wp, unsigned short* __restrict__ Pp) {
  const int lane = threadIdx.x & 63;
  const int w = threadIdx.x >> 6;
  const int nc = blockIdx.x & 7;
  const int c0 = ((blockIdx.x >> 3) * 4 + w) * 16;
  const int l15 = lane & 15, l4 = lane >> 4;

  const float pos = (float)(1023 - (c0 + l15));
  s16x8 a[4];
#pragma unroll
  for (int ks = 0; ks < 4; ++ks)
#pragma unroll
    for (int jj = 0; jj < 8; ++jj) {
      int e = ks * 32 + l4 * 8 + jj;
      int t = e & 63;
      float ang = pos * exp2f(-0.20762050593046014f * (float)t);  // 10000^(-t/64)
      float val = (e < 64) ? sinf(ang) : cosf(ang);
      a[ks][jj] = (short)f2b(val);
    }

  f32x4 acc[8] = {};
#pragma unroll
  for (int fc = 0; fc < 8; ++fc) {
    const float* brow = wp + (nc * 128 + fc * 16 + l15) * 128 + l4 * 8;
    acc[fc] = MFMA(a[0], ldf8(brow), acc[fc]);
    acc[fc] = MFMA(a[1], ldf8(brow + 32), acc[fc]);
    acc[fc] = MFMA(a[2], ldf8(brow + 64), acc[fc]);
    acc[fc] = MFMA(a[3], ldf8(brow + 96), acc[fc]);
  }
#pragma unroll
  for (int fc = 0; fc < 8; ++fc)
#pragma unroll
    for (int r = 0; r < 4; ++r)
      Pp[(nc * 1024 + c0 + l4 * 4 + r) * 128 + fc * 16 + l15] = f2b(acc[fc][r]);
}

// ---------------------------------------------------------------------------
// Flash attention with TXL relative position, Q-projection fused in prologue.
// One wave = 16 q-rows of one (b,h). Barrier-free: per-wave LDS slice + fences.
// LDS 33.8 KB + VGPR<=256 (no spills) -> 4 blocks/CU.
__global__ __launch_bounds__(256, 2) void k_flash(
    const float* __restrict__ x, const float* __restrict__ wq,
    const unsigned short* __restrict__ Kk, const unsigned short* __restrict__ Vt,
    const unsigned short* __restrict__ Pp,
    const float* __restrict__ uu, const float* __restrict__ vv,
    unsigned short* __restrict__ OA) {
  // aliased: prologue q-transform (qu cols 0..127, qv cols 136..263);
  // loop probs (cols 0..63). stride 264 shorts => 2-way bank alias (free).
  __shared__ __align__(16) unsigned short smem[4][16][264];
  const int lane = threadIdx.x & 63;
  const int w = threadIdx.x >> 6;
  const int bh = blockIdx.x & 127;   // blockIdx%8 == h -> per-XCD P_h/K/V locality
  const int grp = blockIdx.x >> 7;   // 0..7
  const int iw = grp * 64 + w * 16;  // 16-row q tile base
  const int b = bh >> 3, h = bh & 7;
  const int l15 = lane & 15, l4 = lane >> 4;
  const float CSCALE = 0.08838834764831845f * 1.4426950408889634f;  // 1/sqrt(128)*log2e

  const unsigned short* K_b = Kk + bh * (1024 * 128);
  const unsigned short* V_b = Vt + bh * (128 * 1024);
  const unsigned short* P_h = Pp + h * (1024 * 128);

  // ---- fused Q projection: q[iw+m][d] = sum_e x[iw+m][b][e] * wq[h*128+d][e]
  s16x8 qu[4], qv[4];
  {
    const float* arow = x + ((iw + l15) * 16 + b) * 128 + l4 * 8;
    s16x8 a0 = ldf8(arow), a1 = ldf8(arow + 32), a2 = ldf8(arow + 64), a3 = ldf8(arow + 96);
    f32x4 qd[8] = {};
#pragma unroll
    for (int fc = 0; fc < 8; ++fc) {
      const float* brow = wq + (h * 128 + fc * 16 + l15) * 128 + l4 * 8;
      qd[fc] = MFMA(a0, ldf8(brow), qd[fc]);
      qd[fc] = MFMA(a1, ldf8(brow + 32), qd[fc]);
      qd[fc] = MFMA(a2, ldf8(brow + 64), qd[fc]);
      qd[fc] = MFMA(a3, ldf8(brow + 96), qd[fc]);
    }
    // D-layout -> LDS (row m=l4*4+r), u/v biases folded
#pragma unroll
    for (int fc = 0; fc < 8; ++fc) {
      float ud = uu[h * 128 + fc * 16 + l15];
      float vd = vv[h * 128 + fc * 16 + l15];
#pragma unroll
      for (int r = 0; r < 4; ++r) {
        smem[w][l4 * 4 + r][fc * 16 + l15] = f2b(qd[fc][r] + ud);
        smem[w][l4 * 4 + r][136 + fc * 16 + l15] = f2b(qd[fc][r] + vd);
      }
    }
    LDS_FENCE();
#pragma unroll
    for (int ks = 0; ks < 4; ++ks) {
      qu[ks] = *(const s16x8*)&smem[w][l15][ks * 32 + l4 * 8];
      qv[ks] = *(const s16x8*)&smem[w][l15][136 + ks * 32 + l4 * 8];
    }
  }

  f32x4 O[8] = {};
  float mrow[4], lrow[4];
#pragma unroll
  for (int r = 0; r < 4; ++r) { mrow[r] = -1e4f; lrow[r] = 0.f; }

  const int ntiles = (iw + 591) >> 6;  // covers j <= iw+15+512, per-wave
  for (int t = 0; t < ntiles; ++t) {
    const int j0 = t * 64;
    const int c0 = j0 - iw + 496;  // band: c = j-i+511; local cc = jj-li+15 in [0,78]

    f32x4 sc[4] = {};
#pragma unroll
    for (int fc = 0; fc < 4; ++fc) {
      const unsigned short* kr = K_b + (j0 + fc * 16 + l15) * 128 + l4 * 8;
#pragma unroll
      for (int ks = 0; ks < 4; ++ks) sc[fc] = MFMA(qu[ks], ldg8(kr + ks * 32), sc[fc]);
    }
    f32x4 sp[5] = {};
#pragma unroll
    for (int pc = 0; pc < 5; ++pc) {
      int c = c0 + pc * 16 + l15;
      c = (c > 1023) ? 1023 : c;  // clamped rows feed only masked elements
      const unsigned short* pr = P_h + c * 128 + l4 * 8;
#pragma unroll
      for (int ks = 0; ks < 4; ++ks) sp[pc] = MFMA(qv[ks], ldg8(pr + ks * 32), sp[pc]);
    }

    // combine content + shfl-gathered position diagonal, mask, scale
    float mt[4] = {-1e4f, -1e4f, -1e4f, -1e4f};
#pragma unroll
    for (int fc = 0; fc < 4; ++fc)
#pragma unroll
      for (int r = 0; r < 4; ++r) {
        int li = l4 * 4 + r;
        int jj = fc * 16 + l15;
        int cc = jj - li + 15;  // cc>>4 in {fc, fc+1}
        int src = (lane & 48) | (cc & 15);
        float g0 = __shfl(sp[fc][r], src, 64);
        float g1 = __shfl(sp[fc + 1][r], src, 64);
        float pv = ((cc >> 4) == fc) ? g0 : g1;
        float logit = (sc[fc][r] + pv) * CSCALE;
        if (j0 + jj > iw + li + 512) logit = -60.0f;  // masked (exp2 ~ 1e-18)
        sc[fc][r] = logit;
        mt[r] = fmaxf(mt[r], logit);
      }

    float alpha[4];
#pragma unroll
    for (int r = 0; r < 4; ++r) {
      float m = mt[r];
#pragma unroll
      for (int off = 1; off < 16; off <<= 1) m = fmaxf(m, __shfl_xor(m, off, 64));
      float mn = fmaxf(mrow[r], m);
      alpha[r] = exp2f(mrow[r] - mn);
      mrow[r] = mn;
    }

    LDS_FENCE();  // prior pa reads drained before overwriting probs
    float rs[4] = {0.f, 0.f, 0.f, 0.f};
#pragma unroll
    for (int fc = 0; fc < 4; ++fc)
#pragma unroll
      for (int r = 0; r < 4; ++r) {
        float p = exp2f(sc[fc][r] - mrow[r]);
        rs[r] += p;
        smem[w][l4 * 4 + r][fc * 16 + l15] = f2b(p);
      }
#pragma unroll
    for (int r = 0; r < 4; ++r) {
      float s = rs[r];
#pragma unroll
      for (int off = 1; off < 16; off <<= 1) s += __shfl_xor(s, off, 64);
      lrow[r] = lrow[r] * alpha[r] + s;
    }
#pragma unroll
    for (int fd = 0; fd < 8; ++fd)
#pragma unroll
      for (int r = 0; r < 4; ++r) O[fd][r] *= alpha[r];

    LDS_FENCE();  // probs written -> A-layout read
    const unsigned short* pb = &smem[w][l15][0];
    s16x8 pa0 = *(const s16x8*)(pb + l4 * 8);
    s16x8 pa1 = *(const s16x8*)(pb + 32 + l4 * 8);
#pragma unroll
    for (int fd = 0; fd < 8; ++fd) {
      const unsigned short* vr = V_b + (fd * 16 + l15) * 1024 + j0 + l4 * 8;
      O[fd] = MFMA(pa0, ldg8(vr), O[fd]);
      O[fd] = MFMA(pa1, ldg8(vr + 32), O[fd]);
    }
  }

  // epilogue: O/l -> OA[i][b][h*128+d]
#pragma unroll
  for (int fd = 0; fd < 8; ++fd)
#pragma unroll
    for (int r = 0; r < 4; ++r) {
      int li = l4 * 4 + r;
      float o = O[fd][r] / fmaxf(lrow[r], 1e-30f);
      OA[((iw + li) * 16 + b) * 1024 + h * 128 + fd * 16 + l15] = f2b(o);
    }
}

// ---------------------------------------------------------------------------
// Output projection: out[i][b][e] = sum_f OA[i][b][f] * wout[e][f], K=1024.
// Block shares wout half; waves split rows. fp32 OUTPUT: layer_out -> out[0]
// and out[2M]; raw fp32 inputs -> out[1M].
__global__ __launch_bounds__(256, 2) void k_out(
    const unsigned short* __restrict__ OA, const float* __restrict__ wout,
    const float* __restrict__ x, float* __restrict__ out) {
  const int lane = threadIdx.x & 63;
  const int w = threadIdx.x >> 6;
  const int half = blockIdx.x & 1;            // block-uniform weight chunk
  const int rt = (blockIdx.x >> 1) * 4 + w;   // i-tile 0..511
  const int l15 = lane & 15, l4 = lane >> 4;

  f32x4 acc[4] = {};
  const unsigned short* arow = OA + (rt * 16 + l15) * 1024 + l4 * 8;
#pragma unroll 4
  for (int ks = 0; ks < 32; ++ks) {
    s16x8 a = ldg8(arow + ks * 32);
#pragma unroll
    for (int fc = 0; fc < 4; ++fc) {
      const float* brow = wout + (half * 64 + fc * 16 + l15) * 1024 + ks * 32 + l4 * 8;
      acc[fc] = MFMA(a, ldf8(brow), acc[fc]);
    }
  }
#pragma unroll
  for (int fc = 0; fc < 4; ++fc)
#pragma unroll
    for (int r = 0; r < 4; ++r) {
      int rg = rt * 16 + l4 * 4 + r;
      int e = half * 64 + fc * 16 + l15;
      float v = acc[fc][r];
      out[rg * 128 + e] = v;
      out[2097152 + rg * 128 + e] = v;
    }
  // copy inputs (fp32) -> out1 (fp32, exact), 1024 floats per wave-chunk
  const float4* src = (const float4*)(x + rt * 2048 + half * 1024);
  float4* dst = (float4*)(out + 1048576 + rt * 2048 + half * 1024);
  dst[lane] = src[lane];
  dst[64 + lane] = src[64 + lane];
  dst[128 + lane] = src[128 + lane];
  dst[192 + lane] = src[192 + lane];
}

// ---------------------------------------------------------------------------
extern "C" void kernel_launch(void* const* d_in, const int* in_sizes, int n_in,
                              void* d_out, int out_size, void* d_ws, size_t ws_size,
                              hipStream_t stream) {
  (void)in_sizes; (void)n_in; (void)out_size; (void)ws_size;
  const float* x    = (const float*)d_in[0];  // [512][16][128] fp32
  const float* mem  = (const float*)d_in[1];  // [2][512][16][128] fp32
  const float* wkv  = (const float*)d_in[2];  // [2048][128] fp32
  const float* wq   = (const float*)d_in[3];  // [1024][128] fp32
  const float* wp   = (const float*)d_in[4];  // [1024][128] fp32
  const float* wout = (const float*)d_in[5];  // [128][1024] fp32
  const float* uu   = (const float*)d_in[6];  // [8][128] fp32
  const float* vv   = (const float*)d_in[7];  // [8][128] fp32
  float* out = (float*)d_out;                 // fp32, 3,145,728 elems
  unsigned short* ws = (unsigned short*)d_ws;

  unsigned short* Kk = ws;             // [16][8][1024][128] 16,777,216
  unsigned short* Vt = ws + 16777216;  // [16][8][128][1024] 16,777,216
  unsigned short* Pp = ws + 33554432;  // [8][1024][128]      1,048,576
  unsigned short* OA = ws + 34603008;  // [512][16][1024]     8,388,608
  // total ws: 42,991,616 bf16 elems = ~82 MB

  k_gemm_kv<<<4096, 256, 0, stream>>>(x, mem, wkv, Kk, Vt);
  k_gemm_p<<<128, 256, 0, stream>>>(wp, Pp);
  k_flash<<<1024, 256, 0, stream>>>(x, wq, Kk, Vt, Pp, uu, vv, OA);
  k_out<<<256, 256, 0, stream>>>(OA, wout, x, out);
}

// Round 8
// 510.463 us; speedup vs baseline: 1.3160x; 1.2518x over previous
//
#include <hip/hip_runtime.h>

// TemporalTX: T=512, B=16, D=128, H=8, DH=128, P=512, J=1024.
// INPUTS fp32; OUTPUT fp32. Workspace intermediates bf16.
// out = [layer_out (1M) | inputs copy (1M) | layer_out copy (1M)] fp32 elems.

typedef short s16x8 __attribute__((ext_vector_type(8)));
typedef float f32x4 __attribute__((ext_vector_type(4)));

#define MFMA(a, b, c) __builtin_amdgcn_mfma_f32_16x16x32_bf16((a), (b), (c), 0, 0, 0)
#define LDS_FENCE() asm volatile("s_waitcnt lgkmcnt(0)" ::: "memory")

__device__ __forceinline__ unsigned short f2b(float f) {
  unsigned int x = __builtin_bit_cast(unsigned int, f);
  x += 0x7fffu + ((x >> 16) & 1u);   // RNE
  return (unsigned short)(x >> 16);
}
__device__ __forceinline__ s16x8 ldg8(const unsigned short* p) {  // bf16 x8
  return *(const s16x8*)p;
}
__device__ __forceinline__ s16x8 ldf8(const float* p) {  // fp32 x8 -> bf16 x8
  float4 u = ((const float4*)p)[0];
  float4 v = ((const float4*)p)[1];
  s16x8 r;
  r[0] = (short)f2b(u.x); r[1] = (short)f2b(u.y);
  r[2] = (short)f2b(u.z); r[3] = (short)f2b(u.w);
  r[4] = (short)f2b(v.x); r[5] = (short)f2b(v.y);
  r[6] = (short)f2b(v.z); r[7] = (short)f2b(v.w);
  return r;
}

// ---------------------------------------------------------------------------
// Weight pre-conversion fp32 -> bf16 (wkv, wq, wp, wout). 8 elems/thread.
__global__ __launch_bounds__(256, 2) void k_prep(
    const float* __restrict__ wkv, const float* __restrict__ wq,
    const float* __restrict__ wp, const float* __restrict__ wout,
    unsigned short* __restrict__ wkv_b, unsigned short* __restrict__ wq_b,
    unsigned short* __restrict__ wp_b, unsigned short* __restrict__ wout_b) {
  int id = blockIdx.x * 256 + threadIdx.x;  // 81920 total
  const float* src;
  unsigned short* dst;
  int off;
  if (id < 32768) { src = wkv; dst = wkv_b; off = id; }
  else if (id < 49152) { src = wq; dst = wq_b; off = id - 32768; }
  else if (id < 65536) { src = wp; dst = wp_b; off = id - 49152; }
  else { src = wout; dst = wout_b; off = id - 65536; }
  ((s16x8*)dst)[off] = ldf8(src + off * 8);
}

// ---------------------------------------------------------------------------
// KV projection over xm = cat(mem0, x). Wave computes TWO 16-row j-groups,
// reusing each B-chunk (bf16 weights) for 2 MFMA chains.
__global__ __launch_bounds__(256, 2) void k_gemm_kv(
    const float* __restrict__ x, const float* __restrict__ mem,
    const unsigned short* __restrict__ wkv_b,
    unsigned short* __restrict__ Kk, unsigned short* __restrict__ Vt) {
  __shared__ float tbuf[4][16][128];
  const int lane = threadIdx.x & 63;
  const int w = threadIdx.x >> 6;
  const int nc = blockIdx.x & 15;          // weight chunk (block-uniform)
  const int b = (blockIdx.x >> 4) & 15;    // batch (block-uniform)
  const int jb = (blockIdx.x >> 8) * 128 + w * 32;  // wave covers jb, jb+16
  const int l15 = lane & 15, l4 = lane >> 4;

  s16x8 A[2][4];
#pragma unroll
  for (int g = 0; g < 2; ++g) {
    int jr = jb + g * 16 + l15;
    const float* arow =
        (jr < 512 ? mem + (jr * 16 + b) * 128 : x + ((jr - 512) * 16 + b) * 128) + l4 * 8;
    A[g][0] = ldf8(arow); A[g][1] = ldf8(arow + 32);
    A[g][2] = ldf8(arow + 64); A[g][3] = ldf8(arow + 96);
  }

  f32x4 acc[2][8] = {};
#pragma unroll
  for (int fc = 0; fc < 8; ++fc) {
    const unsigned short* brow = wkv_b + (nc * 128 + fc * 16 + l15) * 128 + l4 * 8;
    s16x8 b0 = ldg8(brow), b1 = ldg8(brow + 32), b2 = ldg8(brow + 64), b3 = ldg8(brow + 96);
#pragma unroll
    for (int g = 0; g < 2; ++g) {
      acc[g][fc] = MFMA(A[g][0], b0, acc[g][fc]);
      acc[g][fc] = MFMA(A[g][1], b1, acc[g][fc]);
      acc[g][fc] = MFMA(A[g][2], b2, acc[g][fc]);
      acc[g][fc] = MFMA(A[g][3], b3, acc[g][fc]);
    }
  }

  if (nc < 8) {  // K part, h = nc
#pragma unroll
    for (int g = 0; g < 2; ++g)
#pragma unroll
      for (int fc = 0; fc < 8; ++fc)
#pragma unroll
        for (int r = 0; r < 4; ++r) {
          int j = jb + g * 16 + l4 * 4 + r;
          Kk[((b * 8 + nc) * 1024 + j) * 128 + fc * 16 + l15] = f2b(acc[g][fc][r]);
        }
  } else {  // V part, h = nc-8: per-group LDS transpose (per-wave slice)
    const int h = nc - 8;
#pragma unroll
    for (int g = 0; g < 2; ++g) {
      if (g) LDS_FENCE();  // ensure g0 reads done before overwrite
#pragma unroll
      for (int fc = 0; fc < 8; ++fc)
#pragma unroll
        for (int r = 0; r < 4; ++r) tbuf[w][l4 * 4 + r][fc * 16 + l15] = acc[g][fc][r];
      LDS_FENCE();
#pragma unroll
      for (int half = 0; half < 2; ++half) {
        int dd = half * 64 + lane;
        unsigned int wd[8];
#pragma unroll
        for (int pw = 0; pw < 8; ++pw) {
          unsigned int lo = f2b(tbuf[w][2 * pw][dd]);
          unsigned int hi = f2b(tbuf[w][2 * pw + 1][dd]);
          wd[pw] = lo | (hi << 16);
        }
        unsigned short* dst = Vt + ((b * 8 + h) * 128 + dd) * 1024 + jb + g * 16;
        ((uint4*)dst)[0] = make_uint4(wd[0], wd[1], wd[2], wd[3]);
        ((uint4*)dst)[1] = make_uint4(wd[4], wd[5], wd[6], wd[7]);
      }
    }
  }
}

// ---------------------------------------------------------------------------
// P projection: P[h][c][d] = sum_e pe[c][e] * wp[h*128+d][e], pe analytic.
__global__ __launch_bounds__(256, 2) void k_gemm_p(
    const unsigned short* __restrict__ wp_b, unsigned short* __restrict__ Pp) {
  const int lane = threadIdx.x & 63;
  const int w = threadIdx.x >> 6;
  const int nc = blockIdx.x & 7;
  const int c0 = ((blockIdx.x >> 3) * 4 + w) * 16;
  const int l15 = lane & 15, l4 = lane >> 4;

  const float pos = (float)(1023 - (c0 + l15));
  s16x8 a[4];
#pragma unroll
  for (int ks = 0; ks < 4; ++ks)
#pragma unroll
    for (int jj = 0; jj < 8; ++jj) {
      int e = ks * 32 + l4 * 8 + jj;
      int t = e & 63;
      float ang = pos * exp2f(-0.20762050593046014f * (float)t);  // 10000^(-t/64)
      float val = (e < 64) ? sinf(ang) : cosf(ang);
      a[ks][jj] = (short)f2b(val);
    }

  f32x4 acc[8] = {};
#pragma unroll
  for (int fc = 0; fc < 8; ++fc) {
    const unsigned short* brow = wp_b + (nc * 128 + fc * 16 + l15) * 128 + l4 * 8;
    acc[fc] = MFMA(a[0], ldg8(brow), acc[fc]);
    acc[fc] = MFMA(a[1], ldg8(brow + 32), acc[fc]);
    acc[fc] = MFMA(a[2], ldg8(brow + 64), acc[fc]);
    acc[fc] = MFMA(a[3], ldg8(brow + 96), acc[fc]);
  }
#pragma unroll
  for (int fc = 0; fc < 8; ++fc)
#pragma unroll
    for (int r = 0; r < 4; ++r)
      Pp[(nc * 1024 + c0 + l4 * 4 + r) * 128 + fc * 16 + l15] = f2b(acc[fc][r]);
}

// ---------------------------------------------------------------------------
// Flash attention, TXL rel-pos, fused Q-projection. One wave = 16 q-rows.
// Fixed-shift softmax (logits tiny, shift-invariant): no running max/rescale,
// row sums reduced once after the loop. Tile-PAIR (128-wide j) iterations.
__global__ __launch_bounds__(256, 2) void k_flash(
    const float* __restrict__ x, const unsigned short* __restrict__ wq_b,
    const unsigned short* __restrict__ Kk, const unsigned short* __restrict__ Vt,
    const unsigned short* __restrict__ Pp,
    const float* __restrict__ uu, const float* __restrict__ vv,
    unsigned short* __restrict__ OA) {
  // aliased: prologue q-transform (cols 0..263); loop probs (cols 0..127)
  __shared__ __align__(16) unsigned short smem[4][16][264];
  const int lane = threadIdx.x & 63;
  const int w = threadIdx.x >> 6;
  const int bh = blockIdx.x & 127;
  const int grp = 7 - (blockIdx.x >> 7);  // reversed: longest blocks first
  const int iw = grp * 64 + w * 16;
  const int b = bh >> 3, h = bh & 7;
  const int l15 = lane & 15, l4 = lane >> 4;
  const float CSCALE = 0.08838834764831845f * 1.4426950408889634f;  // 1/sqrt(128)*log2e

  const unsigned short* K_b = Kk + bh * (1024 * 128);
  const unsigned short* V_b = Vt + bh * (128 * 1024);
  const unsigned short* P_h = Pp + h * (1024 * 128);

  // ---- fused Q projection (bf16 weights)
  s16x8 qu[4], qv[4];
  {
    const float* arow = x + ((iw + l15) * 16 + b) * 128 + l4 * 8;
    s16x8 a0 = ldf8(arow), a1 = ldf8(arow + 32), a2 = ldf8(arow + 64), a3 = ldf8(arow + 96);
    f32x4 qd[8] = {};
#pragma unroll
    for (int fc = 0; fc < 8; ++fc) {
      const unsigned short* brow = wq_b + (h * 128 + fc * 16 + l15) * 128 + l4 * 8;
      qd[fc] = MFMA(a0, ldg8(brow), qd[fc]);
      qd[fc] = MFMA(a1, ldg8(brow + 32), qd[fc]);
      qd[fc] = MFMA(a2, ldg8(brow + 64), qd[fc]);
      qd[fc] = MFMA(a3, ldg8(brow + 96), qd[fc]);
    }
#pragma unroll
    for (int fc = 0; fc < 8; ++fc) {
      float ud = uu[h * 128 + fc * 16 + l15];
      float vd = vv[h * 128 + fc * 16 + l15];
#pragma unroll
      for (int r = 0; r < 4; ++r) {
        smem[w][l4 * 4 + r][fc * 16 + l15] = f2b(qd[fc][r] + ud);
        smem[w][l4 * 4 + r][136 + fc * 16 + l15] = f2b(qd[fc][r] + vd);
      }
    }
    LDS_FENCE();
#pragma unroll
    for (int ks = 0; ks < 4; ++ks) {
      qu[ks] = *(const s16x8*)&smem[w][l15][ks * 32 + l4 * 8];
      qv[ks] = *(const s16x8*)&smem[w][l15][136 + ks * 32 + l4 * 8];
    }
  }

  f32x4 O[8] = {};
  float rs[4] = {0.f, 0.f, 0.f, 0.f};  // per-lane partial row sums

  const int npairs = (((iw + 591) >> 6) + 1) >> 1;  // <=8 -> j <= 1023, no OOB
  for (int tp = 0; tp < npairs; ++tp) {
    const int j0 = tp * 128;
    const int c0 = j0 - iw + 496;  // band base; cc = jj - li + 15 in [0,142]

    // position band: 9 chunks of 16 P-rows
    f32x4 sp[9];
#pragma unroll
    for (int pc = 0; pc < 9; ++pc) {
      int c = c0 + pc * 16 + l15;
      c = (c > 1023) ? 1023 : c;  // clamped rows feed only masked elements
      const unsigned short* pr = P_h + c * 128 + l4 * 8;
      f32x4 t = {};
      t = MFMA(qv[0], ldg8(pr), t);
      t = MFMA(qv[1], ldg8(pr + 32), t);
      t = MFMA(qv[2], ldg8(pr + 64), t);
      t = MFMA(qv[3], ldg8(pr + 96), t);
      sp[pc] = t;
    }

    LDS_FENCE();  // prior pa reads drained before prob overwrite
    // content per 16-col chunk, combine, exp2, stage probs
#pragma unroll
    for (int fc = 0; fc < 8; ++fc) {
      const unsigned short* kr = K_b + (j0 + fc * 16 + l15) * 128 + l4 * 8;
      f32x4 scf = {};
      scf = MFMA(qu[0], ldg8(kr), scf);
      scf = MFMA(qu[1], ldg8(kr + 32), scf);
      scf = MFMA(qu[2], ldg8(kr + 64), scf);
      scf = MFMA(qu[3], ldg8(kr + 96), scf);
#pragma unroll
      for (int r = 0; r < 4; ++r) {
        int li = l4 * 4 + r;
        int jj = fc * 16 + l15;
        int cc = jj - li + 15;  // cc>>4 in {fc, fc+1}
        int src = (lane & 48) | (cc & 15);
        float g0 = __shfl(sp[fc][r], src, 64);
        float g1 = __shfl(sp[fc + 1][r], src, 64);
        float pv = ((cc >> 4) == fc) ? g0 : g1;
        float logit = (scf[r] + pv) * CSCALE - 12.0f;  // fixed shift 2^-12
        if (j0 + jj > iw + li + 512) logit = -72.0f;   // masked
        float p = exp2f(logit);
        rs[r] += p;
        smem[w][li][jj] = f2b(p);
      }
    }

    LDS_FENCE();  // probs visible -> A-layout read
    const unsigned short* pb = &smem[w][l15][0];
    s16x8 pa0 = *(const s16x8*)(pb + l4 * 8);
    s16x8 pa1 = *(const s16x8*)(pb + 32 + l4 * 8);
    s16x8 pa2 = *(const s16x8*)(pb + 64 + l4 * 8);
    s16x8 pa3 = *(const s16x8*)(pb + 96 + l4 * 8);
#pragma unroll
    for (int fd = 0; fd < 8; ++fd) {
      const unsigned short* vr = V_b + (fd * 16 + l15) * 1024 + j0 + l4 * 8;
      O[fd] = MFMA(pa0, ldg8(vr), O[fd]);
      O[fd] = MFMA(pa1, ldg8(vr + 32), O[fd]);
      O[fd] = MFMA(pa2, ldg8(vr + 64), O[fd]);
      O[fd] = MFMA(pa3, ldg8(vr + 96), O[fd]);
    }
  }

  // one-time row-sum reduction (over the 16 lanes of each l4 group)
  float lrow[4];
#pragma unroll
  for (int r = 0; r < 4; ++r) {
    float s = rs[r];
#pragma unroll
    for (int off = 1; off < 16; off <<= 1) s += __shfl_xor(s, off, 64);
    lrow[r] = s;
  }

  // epilogue: O/l -> OA[i][b][h*128+d]
#pragma unroll
  for (int fd = 0; fd < 8; ++fd)
#pragma unroll
    for (int r = 0; r < 4; ++r) {
      int li = l4 * 4 + r;
      float o = O[fd][r] / lrow[r];
      OA[((iw + li) * 16 + b) * 1024 + h * 128 + fd * 16 + l15] = f2b(o);
    }
}

// ---------------------------------------------------------------------------
// Output projection: out[i][b][e] = sum_f OA[i][b][f] * wout[e][f], K=1024.
// bf16 weights. fp32 OUTPUT: layer_out -> out[0], out[2M]; inputs -> out[1M].
__global__ __launch_bounds__(256, 2) void k_out(
    const unsigned short* __restrict__ OA, const unsigned short* __restrict__ wout_b,
    const float* __restrict__ x, float* __restrict__ out) {
  const int lane = threadIdx.x & 63;
  const int w = threadIdx.x >> 6;
  const int half = blockIdx.x & 1;            // block-uniform weight chunk
  const int rt = (blockIdx.x >> 1) * 4 + w;   // i-tile 0..511
  const int l15 = lane & 15, l4 = lane >> 4;

  f32x4 acc[4] = {};
  const unsigned short* arow = OA + (rt * 16 + l15) * 1024 + l4 * 8;
#pragma unroll 4
  for (int ks = 0; ks < 32; ++ks) {
    s16x8 a = ldg8(arow + ks * 32);
#pragma unroll
    for (int fc = 0; fc < 4; ++fc) {
      const unsigned short* brow =
          wout_b + (half * 64 + fc * 16 + l15) * 1024 + ks * 32 + l4 * 8;
      acc[fc] = MFMA(a, ldg8(brow), acc[fc]);
    }
  }
#pragma unroll
  for (int fc = 0; fc < 4; ++fc)
#pragma unroll
    for (int r = 0; r < 4; ++r) {
      int rg = rt * 16 + l4 * 4 + r;
      int e = half * 64 + fc * 16 + l15;
      float v = acc[fc][r];
      out[rg * 128 + e] = v;
      out[2097152 + rg * 128 + e] = v;
    }
  // copy inputs (fp32) -> out1 (fp32, exact)
  const float4* src = (const float4*)(x + rt * 2048 + half * 1024);
  float4* dst = (float4*)(out + 1048576 + rt * 2048 + half * 1024);
  dst[lane] = src[lane];
  dst[64 + lane] = src[64 + lane];
  dst[128 + lane] = src[128 + lane];
  dst[192 + lane] = src[192 + lane];
}

// ---------------------------------------------------------------------------
extern "C" void kernel_launch(void* const* d_in, const int* in_sizes, int n_in,
                              void* d_out, int out_size, void* d_ws, size_t ws_size,
                              hipStream_t stream) {
  (void)in_sizes; (void)n_in; (void)out_size; (void)ws_size;
  const float* x    = (const float*)d_in[0];  // [512][16][128] fp32
  const float* mem  = (const float*)d_in[1];  // [2][512][16][128] fp32
  const float* wkv  = (const float*)d_in[2];  // [2048][128] fp32
  const float* wq   = (const float*)d_in[3];  // [1024][128] fp32
  const float* wp   = (const float*)d_in[4];  // [1024][128] fp32
  const float* wout = (const float*)d_in[5];  // [128][1024] fp32
  const float* uu   = (const float*)d_in[6];  // [8][128] fp32
  const float* vv   = (const float*)d_in[7];  // [8][128] fp32
  float* out = (float*)d_out;                 // fp32, 3,145,728 elems
  unsigned short* ws = (unsigned short*)d_ws;

  unsigned short* Kk     = ws;             // [16][8][1024][128] 16,777,216
  unsigned short* Vt     = ws + 16777216;  // [16][8][128][1024] 16,777,216
  unsigned short* Pp     = ws + 33554432;  // [8][1024][128]      1,048,576
  unsigned short* OA     = ws + 34603008;  // [512][16][1024]     8,388,608
  unsigned short* wkv_b  = ws + 42991616;  // 262,144
  unsigned short* wq_b   = ws + 43253760;  // 131,072
  unsigned short* wp_b   = ws + 43384832;  // 131,072
  unsigned short* wout_b = ws + 43515904;  // 131,072 -> end 43,646,976 (~83.3 MB)

  k_prep<<<320, 256, 0, stream>>>(wkv, wq, wp, wout, wkv_b, wq_b, wp_b, wout_b);
  k_gemm_kv<<<2048, 256, 0, stream>>>(x, mem, wkv_b, Kk, Vt);
  k_gemm_p<<<128, 256, 0, stream>>>(wp_b, Pp);
  k_flash<<<1024, 256, 0, stream>>>(x, wq_b, Kk, Vt, Pp, uu, vv, OA);
  k_out<<<256, 256, 0, stream>>>(OA, wout_b, x, out);
}

// Round 9
// 507.603 us; speedup vs baseline: 1.3234x; 1.0056x over previous
//
#include <hip/hip_runtime.h>

// TemporalTX: T=512, B=16, D=128, H=8, DH=128, P=512, J=1024.
// INPUTS fp32; OUTPUT fp32. Workspace intermediates bf16.
// out = [layer_out (1M) | inputs copy (1M) | layer_out copy (1M)] fp32 elems.

typedef short s16x8 __attribute__((ext_vector_type(8)));
typedef float f32x4 __attribute__((ext_vector_type(4)));

#define MFMA(a, b, c) __builtin_amdgcn_mfma_f32_16x16x32_bf16((a), (b), (c), 0, 0, 0)
#define LDS_FENCE() asm volatile("s_waitcnt lgkmcnt(0)" ::: "memory")

__device__ __forceinline__ unsigned short f2b(float f) {
  unsigned int x = __builtin_bit_cast(unsigned int, f);
  x += 0x7fffu + ((x >> 16) & 1u);   // RNE
  return (unsigned short)(x >> 16);
}
__device__ __forceinline__ s16x8 ldg8(const unsigned short* p) {  // bf16 x8
  return *(const s16x8*)p;
}
__device__ __forceinline__ s16x8 ldf8(const float* p) {  // fp32 x8 -> bf16 x8
  float4 u = ((const float4*)p)[0];
  float4 v = ((const float4*)p)[1];
  s16x8 r;
  r[0] = (short)f2b(u.x); r[1] = (short)f2b(u.y);
  r[2] = (short)f2b(u.z); r[3] = (short)f2b(u.w);
  r[4] = (short)f2b(v.x); r[5] = (short)f2b(v.y);
  r[6] = (short)f2b(v.z); r[7] = (short)f2b(v.w);
  return r;
}

// ---------------------------------------------------------------------------
// Weight pre-conversion fp32 -> bf16 (wkv, wq, wp, wout). 8 elems/thread.
__global__ __launch_bounds__(256, 2) void k_prep(
    const float* __restrict__ wkv, const float* __restrict__ wq,
    const float* __restrict__ wp, const float* __restrict__ wout,
    unsigned short* __restrict__ wkv_b, unsigned short* __restrict__ wq_b,
    unsigned short* __restrict__ wp_b, unsigned short* __restrict__ wout_b) {
  int id = blockIdx.x * 256 + threadIdx.x;  // 81920 total
  const float* src;
  unsigned short* dst;
  int off;
  if (id < 32768) { src = wkv; dst = wkv_b; off = id; }
  else if (id < 49152) { src = wq; dst = wq_b; off = id - 32768; }
  else if (id < 65536) { src = wp; dst = wp_b; off = id - 49152; }
  else { src = wout; dst = wout_b; off = id - 65536; }
  ((s16x8*)dst)[off] = ldf8(src + off * 8);
}

// ---------------------------------------------------------------------------
// KV projection over xm = cat(mem0, x). Block = (ncgrp of 4, b, 128-j range);
// waves split j (2 groups of 16 each). A-fragments loaded ONCE, reused for
// 4 weight chunks (A-traffic /4). bf16 weights.
__global__ __launch_bounds__(256, 2) void k_gemm_kv(
    const float* __restrict__ x, const float* __restrict__ mem,
    const unsigned short* __restrict__ wkv_b,
    unsigned short* __restrict__ Kk, unsigned short* __restrict__ Vt) {
  __shared__ float tbuf[4][16][128];
  const int lane = threadIdx.x & 63;
  const int w = threadIdx.x >> 6;
  const int ncg = (blockIdx.x & 3) * 4;            // 0,4,8,12 (block-uniform)
  const int b = (blockIdx.x >> 2) & 15;            // batch (block-uniform)
  const int jb = (blockIdx.x >> 6) * 128 + w * 32; // wave covers jb, jb+16
  const int l15 = lane & 15, l4 = lane >> 4;

  s16x8 A[2][4];
#pragma unroll
  for (int g = 0; g < 2; ++g) {
    int jr = jb + g * 16 + l15;
    const float* arow =
        (jr < 512 ? mem + (jr * 16 + b) * 128 : x + ((jr - 512) * 16 + b) * 128) + l4 * 8;
    A[g][0] = ldf8(arow); A[g][1] = ldf8(arow + 32);
    A[g][2] = ldf8(arow + 64); A[g][3] = ldf8(arow + 96);
  }

  for (int q = 0; q < 4; ++q) {
    const int nc = ncg + q;
    f32x4 acc[2][8] = {};
#pragma unroll
    for (int fc = 0; fc < 8; ++fc) {
      const unsigned short* brow = wkv_b + (nc * 128 + fc * 16 + l15) * 128 + l4 * 8;
      s16x8 b0 = ldg8(brow), b1 = ldg8(brow + 32), b2 = ldg8(brow + 64), b3 = ldg8(brow + 96);
#pragma unroll
      for (int g = 0; g < 2; ++g) {
        acc[g][fc] = MFMA(A[g][0], b0, acc[g][fc]);
        acc[g][fc] = MFMA(A[g][1], b1, acc[g][fc]);
        acc[g][fc] = MFMA(A[g][2], b2, acc[g][fc]);
        acc[g][fc] = MFMA(A[g][3], b3, acc[g][fc]);
      }
    }

    if (nc < 8) {  // K part, h = nc
#pragma unroll
      for (int g = 0; g < 2; ++g)
#pragma unroll
        for (int fc = 0; fc < 8; ++fc)
#pragma unroll
          for (int r = 0; r < 4; ++r) {
            int j = jb + g * 16 + l4 * 4 + r;
            Kk[((b * 8 + nc) * 1024 + j) * 128 + fc * 16 + l15] = f2b(acc[g][fc][r]);
          }
    } else {  // V part, h = nc-8: per-group LDS transpose (per-wave slice)
      const int h = nc - 8;
#pragma unroll
      for (int g = 0; g < 2; ++g) {
        LDS_FENCE();  // prior reads done before overwrite
#pragma unroll
        for (int fc = 0; fc < 8; ++fc)
#pragma unroll
          for (int r = 0; r < 4; ++r) tbuf[w][l4 * 4 + r][fc * 16 + l15] = acc[g][fc][r];
        LDS_FENCE();
#pragma unroll
        for (int half = 0; half < 2; ++half) {
          int dd = half * 64 + lane;
          unsigned int wd[8];
#pragma unroll
          for (int pw = 0; pw < 8; ++pw) {
            unsigned int lo = f2b(tbuf[w][2 * pw][dd]);
            unsigned int hi = f2b(tbuf[w][2 * pw + 1][dd]);
            wd[pw] = lo | (hi << 16);
          }
          unsigned short* dst = Vt + ((b * 8 + h) * 128 + dd) * 1024 + jb + g * 16;
          ((uint4*)dst)[0] = make_uint4(wd[0], wd[1], wd[2], wd[3]);
          ((uint4*)dst)[1] = make_uint4(wd[4], wd[5], wd[6], wd[7]);
        }
      }
    }
  }
}

// ---------------------------------------------------------------------------
// P projection: P[h][c][d] = sum_e pe[c][e] * wp[h*128+d][e], pe analytic.
__global__ __launch_bounds__(256, 2) void k_gemm_p(
    const unsigned short* __restrict__ wp_b, unsigned short* __restrict__ Pp) {
  const int lane = threadIdx.x & 63;
  const int w = threadIdx.x >> 6;
  const int nc = blockIdx.x & 7;
  const int c0 = ((blockIdx.x >> 3) * 4 + w) * 16;
  const int l15 = lane & 15, l4 = lane >> 4;

  const float pos = (float)(1023 - (c0 + l15));
  s16x8 a[4];
#pragma unroll
  for (int ks = 0; ks < 4; ++ks)
#pragma unroll
    for (int jj = 0; jj < 8; ++jj) {
      int e = ks * 32 + l4 * 8 + jj;
      int t = e & 63;
      float ang = pos * exp2f(-0.20762050593046014f * (float)t);  // 10000^(-t/64)
      float val = (e < 64) ? sinf(ang) : cosf(ang);
      a[ks][jj] = (short)f2b(val);
    }

  f32x4 acc[8] = {};
#pragma unroll
  for (int fc = 0; fc < 8; ++fc) {
    const unsigned short* brow = wp_b + (nc * 128 + fc * 16 + l15) * 128 + l4 * 8;
    acc[fc] = MFMA(a[0], ldg8(brow), acc[fc]);
    acc[fc] = MFMA(a[1], ldg8(brow + 32), acc[fc]);
    acc[fc] = MFMA(a[2], ldg8(brow + 64), acc[fc]);
    acc[fc] = MFMA(a[3], ldg8(brow + 96), acc[fc]);
  }
#pragma unroll
  for (int fc = 0; fc < 8; ++fc)
#pragma unroll
    for (int r = 0; r < 4; ++r)
      Pp[(nc * 1024 + c0 + l4 * 4 + r) * 128 + fc * 16 + l15] = f2b(acc[fc][r]);
}

// ---------------------------------------------------------------------------
// Flash attention, TXL rel-pos, fused Q-projection. One wave = 16 q-rows.
// Fixed-shift softmax. Tile-pair (128-j) iterations. NO fences in the loop:
// same-wave DS ordering + compiler memory deps handle prob write->read; the
// scheduler is free to hoist independent V/K/P global loads for MLP.
// LDS 17.4 KB ([4][16][136], two-pass qu/qv prologue transform).
__global__ __launch_bounds__(256, 2) void k_flash(
    const float* __restrict__ x, const unsigned short* __restrict__ wq_b,
    const unsigned short* __restrict__ Kk, const unsigned short* __restrict__ Vt,
    const unsigned short* __restrict__ Pp,
    const float* __restrict__ uu, const float* __restrict__ vv,
    unsigned short* __restrict__ OA) {
  __shared__ __align__(16) unsigned short smem[4][16][136];  // stride 272B
  const int lane = threadIdx.x & 63;
  const int w = threadIdx.x >> 6;
  const int bh = blockIdx.x & 127;
  const int grp = 7 - (blockIdx.x >> 7);  // reversed: longest blocks first
  const int iw = grp * 64 + w * 16;
  const int b = bh >> 3, h = bh & 7;
  const int l15 = lane & 15, l4 = lane >> 4;
  const float CSCALE = 0.08838834764831845f * 1.4426950408889634f;  // 1/sqrt(128)*log2e

  const unsigned short* K_b = Kk + bh * (1024 * 128);
  const unsigned short* V_b = Vt + bh * (128 * 1024);
  const unsigned short* P_h = Pp + h * (1024 * 128);

  // ---- fused Q projection (bf16 weights), two-pass D->A transform
  s16x8 qu[4], qv[4];
  {
    const float* arow = x + ((iw + l15) * 16 + b) * 128 + l4 * 8;
    s16x8 a0 = ldf8(arow), a1 = ldf8(arow + 32), a2 = ldf8(arow + 64), a3 = ldf8(arow + 96);
    f32x4 qd[8] = {};
#pragma unroll
    for (int fc = 0; fc < 8; ++fc) {
      const unsigned short* brow = wq_b + (h * 128 + fc * 16 + l15) * 128 + l4 * 8;
      qd[fc] = MFMA(a0, ldg8(brow), qd[fc]);
      qd[fc] = MFMA(a1, ldg8(brow + 32), qd[fc]);
      qd[fc] = MFMA(a2, ldg8(brow + 64), qd[fc]);
      qd[fc] = MFMA(a3, ldg8(brow + 96), qd[fc]);
    }
    // pass 1: qu
#pragma unroll
    for (int fc = 0; fc < 8; ++fc) {
      float ud = uu[h * 128 + fc * 16 + l15];
#pragma unroll
      for (int r = 0; r < 4; ++r)
        smem[w][l4 * 4 + r][fc * 16 + l15] = f2b(qd[fc][r] + ud);
    }
    LDS_FENCE();
#pragma unroll
    for (int ks = 0; ks < 4; ++ks)
      qu[ks] = *(const s16x8*)&smem[w][l15][ks * 32 + l4 * 8];
    LDS_FENCE();
    // pass 2: qv (same buffer)
#pragma unroll
    for (int fc = 0; fc < 8; ++fc) {
      float vd = vv[h * 128 + fc * 16 + l15];
#pragma unroll
      for (int r = 0; r < 4; ++r)
        smem[w][l4 * 4 + r][fc * 16 + l15] = f2b(qd[fc][r] + vd);
    }
    LDS_FENCE();
#pragma unroll
    for (int ks = 0; ks < 4; ++ks)
      qv[ks] = *(const s16x8*)&smem[w][l15][ks * 32 + l4 * 8];
  }

  f32x4 O[8] = {};
  float rs[4] = {0.f, 0.f, 0.f, 0.f};  // per-lane partial row sums

  const int npairs = (((iw + 591) >> 6) + 1) >> 1;  // <=8 -> j <= 1023, no OOB
  for (int tp = 0; tp < npairs; ++tp) {
    const int j0 = tp * 128;
    const int c0 = j0 - iw + 496;  // band base; cc = jj - li + 15 in [0,142]

    // position band: 9 chunks of 16 P-rows
    f32x4 sp[9];
#pragma unroll
    for (int pc = 0; pc < 9; ++pc) {
      int c = c0 + pc * 16 + l15;
      c = (c > 1023) ? 1023 : c;  // clamped rows feed only masked elements
      const unsigned short* pr = P_h + c * 128 + l4 * 8;
      f32x4 t = {};
      t = MFMA(qv[0], ldg8(pr), t);
      t = MFMA(qv[1], ldg8(pr + 32), t);
      t = MFMA(qv[2], ldg8(pr + 64), t);
      t = MFMA(qv[3], ldg8(pr + 96), t);
      sp[pc] = t;
    }

    // content per 16-col chunk, combine, exp2, stage probs
#pragma unroll
    for (int fc = 0; fc < 8; ++fc) {
      const unsigned short* kr = K_b + (j0 + fc * 16 + l15) * 128 + l4 * 8;
      f32x4 scf = {};
      scf = MFMA(qu[0], ldg8(kr), scf);
      scf = MFMA(qu[1], ldg8(kr + 32), scf);
      scf = MFMA(qu[2], ldg8(kr + 64), scf);
      scf = MFMA(qu[3], ldg8(kr + 96), scf);
#pragma unroll
      for (int r = 0; r < 4; ++r) {
        int li = l4 * 4 + r;
        int jj = fc * 16 + l15;
        int cc = jj - li + 15;  // cc>>4 in {fc, fc+1}
        int src = (lane & 48) | (cc & 15);
        float g0 = __shfl(sp[fc][r], src, 64);
        float g1 = __shfl(sp[fc + 1][r], src, 64);
        float pv = ((cc >> 4) == fc) ? g0 : g1;
        float logit = (scf[r] + pv) * CSCALE - 12.0f;  // fixed shift 2^-12
        if (j0 + jj > iw + li + 512) logit = -72.0f;   // masked
        float p = exp2f(logit);
        rs[r] += p;
        smem[w][li][jj] = f2b(p);
      }
    }

    // probs -> A-layout read (compiler orders via LDS memory deps)
    const unsigned short* pb = &smem[w][l15][0];
    s16x8 pa0 = *(const s16x8*)(pb + l4 * 8);
    s16x8 pa1 = *(const s16x8*)(pb + 32 + l4 * 8);
    s16x8 pa2 = *(const s16x8*)(pb + 64 + l4 * 8);
    s16x8 pa3 = *(const s16x8*)(pb + 96 + l4 * 8);
#pragma unroll
    for (int fd = 0; fd < 8; ++fd) {
      const unsigned short* vr = V_b + (fd * 16 + l15) * 1024 + j0 + l4 * 8;
      O[fd] = MFMA(pa0, ldg8(vr), O[fd]);
      O[fd] = MFMA(pa1, ldg8(vr + 32), O[fd]);
      O[fd] = MFMA(pa2, ldg8(vr + 64), O[fd]);
      O[fd] = MFMA(pa3, ldg8(vr + 96), O[fd]);
    }
  }

  // one-time row-sum reduction (over the 16 lanes of each l4 group)
  float lrow[4];
#pragma unroll
  for (int r = 0; r < 4; ++r) {
    float s = rs[r];
#pragma unroll
    for (int off = 1; off < 16; off <<= 1) s += __shfl_xor(s, off, 64);
    lrow[r] = s;
  }

  // epilogue: O/l -> OA[i][b][h*128+d]
#pragma unroll
  for (int fd = 0; fd < 8; ++fd)
#pragma unroll
    for (int r = 0; r < 4; ++r) {
      int li = l4 * 4 + r;
      float o = O[fd][r] / lrow[r];
      OA[((iw + li) * 16 + b) * 1024 + h * 128 + fd * 16 + l15] = f2b(o);
    }
}

// ---------------------------------------------------------------------------
// Output projection: out[i][b][e] = sum_f OA[i][b][f] * wout[e][f], K=1024.
// bf16 weights. fp32 OUTPUT: layer_out -> out[0], out[2M]; inputs -> out[1M].
__global__ __launch_bounds__(256, 2) void k_out(
    const unsigned short* __restrict__ OA, const unsigned short* __restrict__ wout_b,
    const float* __restrict__ x, float* __restrict__ out) {
  const int lane = threadIdx.x & 63;
  const int w = threadIdx.x >> 6;
  const int half = blockIdx.x & 1;            // block-uniform weight chunk
  const int rt = (blockIdx.x >> 1) * 4 + w;   // i-tile 0..511
  const int l15 = lane & 15, l4 = lane >> 4;

  f32x4 acc[4] = {};
  const unsigned short* arow = OA + (rt * 16 + l15) * 1024 + l4 * 8;
#pragma unroll 4
  for (int ks = 0; ks < 32; ++ks) {
    s16x8 a = ldg8(arow + ks * 32);
#pragma unroll
    for (int fc = 0; fc < 4; ++fc) {
      const unsigned short* brow =
          wout_b + (half * 64 + fc * 16 + l15) * 1024 + ks * 32 + l4 * 8;
      acc[fc] = MFMA(a, ldg8(brow), acc[fc]);
    }
  }
#pragma unroll
  for (int fc = 0; fc < 4; ++fc)
#pragma unroll
    for (int r = 0; r < 4; ++r) {
      int rg = rt * 16 + l4 * 4 + r;
      int e = half * 64 + fc * 16 + l15;
      float v = acc[fc][r];
      out[rg * 128 + e] = v;
      out[2097152 + rg * 128 + e] = v;
    }
  // copy inputs (fp32) -> out1 (fp32, exact)
  const float4* src = (const float4*)(x + rt * 2048 + half * 1024);
  float4* dst = (float4*)(out + 1048576 + rt * 2048 + half * 1024);
  dst[lane] = src[lane];
  dst[64 + lane] = src[64 + lane];
  dst[128 + lane] = src[128 + lane];
  dst[192 + lane] = src[192 + lane];
}

// ---------------------------------------------------------------------------
extern "C" void kernel_launch(void* const* d_in, const int* in_sizes, int n_in,
                              void* d_out, int out_size, void* d_ws, size_t ws_size,
                              hipStream_t stream) {
  (void)in_sizes; (void)n_in; (void)out_size; (void)ws_size;
  const float* x    = (const float*)d_in[0];  // [512][16][128] fp32
  const float* mem  = (const float*)d_in[1];  // [2][512][16][128] fp32
  const float* wkv  = (const float*)d_in[2];  // [2048][128] fp32
  const float* wq   = (const float*)d_in[3];  // [1024][128] fp32
  const float* wp   = (const float*)d_in[4];  // [1024][128] fp32
  const float* wout = (const float*)d_in[5];  // [128][1024] fp32
  const float* uu   = (const float*)d_in[6];  // [8][128] fp32
  const float* vv   = (const float*)d_in[7];  // [8][128] fp32
  float* out = (float*)d_out;                 // fp32, 3,145,728 elems
  unsigned short* ws = (unsigned short*)d_ws;

  unsigned short* Kk     = ws;             // [16][8][1024][128] 16,777,216
  unsigned short* Vt     = ws + 16777216;  // [16][8][128][1024] 16,777,216
  unsigned short* Pp     = ws + 33554432;  // [8][1024][128]      1,048,576
  unsigned short* OA     = ws + 34603008;  // [512][16][1024]     8,388,608
  unsigned short* wkv_b  = ws + 42991616;  // 262,144
  unsigned short* wq_b   = ws + 43253760;  // 131,072
  unsigned short* wp_b   = ws + 43384832;  // 131,072
  unsigned short* wout_b = ws + 43515904;  // 131,072 -> end 43,646,976 (~83.3 MB)

  k_prep<<<320, 256, 0, stream>>>(wkv, wq, wp, wout, wkv_b, wq_b, wp_b, wout_b);
  k_gemm_kv<<<512, 256, 0, stream>>>(x, mem, wkv_b, Kk, Vt);
  k_gemm_p<<<128, 256, 0, stream>>>(wp_b, Pp);
  k_flash<<<1024, 256, 0, stream>>>(x, wq_b, Kk, Vt, Pp, uu, vv, OA);
  k_out<<<256, 256, 0, stream>>>(OA, wout_b, x, out);
}